// Round 2
// 3602.698 us; speedup vs baseline: 1.5774x; 1.5774x over previous
//
#include <hip/hip_runtime.h>

// VQ: z [32,256,64,64] f32, codebook [1024,256] f32 -> out [32,256,64,64] f32
// Coarse pass: s[pix][code] via bf16 double-split MFMA (hi*hi + hi*lo + lo*hi),
// score = s - 0.5*||e||^2, per-pixel top-2. Pixels with top-2 gap < MARGIN are
// flagged into a bitmap and re-resolved by a SEPARATE rescan kernel running the
// round-3-validated numpy-bitwise full rescan (verbatim math).
// Split rationale: inline rescan re-streamed 1MB codebook per flagged pixel
// (~5.5K pixels -> 5.6 GB HBM FETCH, L2-thrashed, serialized per block).
// Dedicated kernel keeps the codebook L2-resident and parallelizes per-pixel.
// Bitmap/t2 live in __device__ globals (module-load allocation): no d_ws
// dependence, no hipMemsetAsync in kernel_launch (graph-capture safe).

typedef float  f32x4 __attribute__((ext_vector_type(4)));
typedef short  s16x8 __attribute__((ext_vector_type(8)));

#define HWSZ   4096
#define DIM    256
#define KCODES 1024
#define MARGIN 1e-4f
#define NPIX   131072
#define NBMW   (NPIX / 32)     // 4096 bitmap words

__device__ unsigned g_bitmap[NBMW];
__device__ float    g_t2[KCODES];

__device__ __forceinline__ unsigned short bf16_rn(float f) {
    unsigned u = __float_as_uint(f);
    unsigned r = u + 0x7fffu + ((u >> 16) & 1u);
    return (unsigned short)(r >> 16);
}
__device__ __forceinline__ float bf16_tof(unsigned short h) {
    return __uint_as_float(((unsigned)h) << 16);
}

// ---- numpy-bitwise helpers (validated round 3): fp contraction OFF ----
__device__ __forceinline__ float np_sumsq_row(const float4* v4) {
    #pragma clang fp contract(off)
    float res0 = 0.f, res1 = 0.f;
    for (int h = 0; h < 2; ++h) {
        const float4* p = v4 + h * 32;          // 128 floats
        float4 a = p[0], b = p[1];
        float r0 = a.x*a.x, r1 = a.y*a.y, r2 = a.z*a.z, r3 = a.w*a.w;
        float r4 = b.x*b.x, r5 = b.y*b.y, r6 = b.z*b.z, r7 = b.w*b.w;
        for (int i = 1; i < 16; ++i) {
            a = p[2*i]; b = p[2*i+1];
            r0 += a.x*a.x; r1 += a.y*a.y; r2 += a.z*a.z; r3 += a.w*a.w;
            r4 += b.x*b.x; r5 += b.y*b.y; r6 += b.z*b.z; r7 += b.w*b.w;
        }
        float s = ((r0+r1)+(r2+r3))+((r4+r5)+(r6+r7));
        if (h == 0) res0 = s; else res1 = s;
    }
    return res0 + res1;
}
__device__ __forceinline__ float np_dot_sse(const float4* z4, const float4* e4) {
    #pragma clang fp contract(off)
    float A0 = 0.f, A1 = 0.f, A2 = 0.f, A3 = 0.f;
    for (int i = 0; i < 64; ++i) {
        float4 zv = z4[i], ev = e4[i];
        A0 += zv.x*ev.x; A1 += zv.y*ev.y; A2 += zv.z*ev.z; A3 += zv.w*ev.w;
    }
    return (A0+A1)+(A2+A3);
}
__device__ __forceinline__ float np_d(float t1, float t2, float s) {
    #pragma clang fp contract(off)
    float T = t1 + t2;
    float U = 2.0f * s;
    return T - U;
}

// ---- kernel 0: zero bitmap + np-exact ||e||^2 table (bitwise same fn) ----
__global__ void kvq_t2(const float* __restrict__ cb) {
    const int k = blockIdx.x * 256 + threadIdx.x;   // 0..1023
    g_t2[k] = np_sumsq_row((const float4*)(cb + (size_t)k * DIM));
    #pragma unroll
    for (int j = 0; j < 4; ++j) g_bitmap[k + 1024 * j] = 0u;
}

// ---- kernel 1: coarse top-2 + gather write + flag bitmap ----
__global__ __launch_bounds__(256, 2)
void kvq_coarse(const float* __restrict__ z, const float* __restrict__ cb,
                float* __restrict__ out) {
    __shared__ s16x8 Bbuf[2][8][2][64];   // [buf][kstep][hi/lo][lane] 16B frags, 32 KB
    __shared__ float hn_s[KCODES];        // 0.5*||e||^2 (fast-path, fma-accurate)
    __shared__ float s1_s[128], s2_s[128];
    __shared__ int   k1_s[128];

    const int t = threadIdx.x;
    const int l = t & 63, w = t >> 6;     // lane, wave
    const int n = l & 15, q = l >> 4;     // frag col / quad
    const int pix0 = blockIdx.x * 128;    // 128 pixels per block
    const int b   = pix0 >> 12;
    const int hw0 = pix0 & 4095;

    for (int i = t; i < KCODES; i += 256) hn_s[i] = 0.f;

    // ---- A fragments: wave w owns pixels [w*32, w*32+32). tile 0/1 = 16 pixels.
    // A[m=lane&15][k=quad*8+j], ch = ks*32 + q*8 + j  (m120-verified layout)
    s16x8 Ahi[2][8], Alo[2][8];
    #pragma unroll
    for (int tile = 0; tile < 2; ++tile) {
        const float* zp = z + (size_t)b * DIM * HWSZ + hw0 + w * 32 + tile * 16 + n;
        #pragma unroll
        for (int ks = 0; ks < 8; ++ks) {
            #pragma unroll
            for (int j = 0; j < 8; ++j) {
                float v = zp[(size_t)(ks * 32 + q * 8 + j) * HWSZ];
                unsigned short h = bf16_rn(v);
                float r = v - bf16_tof(h);
                Ahi[tile][ks][j] = (short)h;
                Alo[tile][ks][j] = (short)bf16_rn(r);
            }
        }
    }
    __syncthreads();   // hn_s zeroed

    // ---- B staging: group g = 16 codes -> frag-ordered LDS + hn atomics ----
    auto stage = [&](int g, int buf) {
        const int nn = t >> 4;                     // code within group
        const int k  = g * 16 + nn;
        const int c0 = (t & 15) * 16;              // 16 channels
        const float4* src = (const float4*)(cb + (size_t)k * DIM + c0);
        float4 v0 = src[0], v1 = src[1], v2 = src[2], v3 = src[3];
        float vv[16] = {v0.x,v0.y,v0.z,v0.w, v1.x,v1.y,v1.z,v1.w,
                        v2.x,v2.y,v2.z,v2.w, v3.x,v3.y,v3.z,v3.w};
        float p = 0.f;
        #pragma unroll
        for (int i = 0; i < 16; ++i) p = fmaf(vv[i], vv[i], p);
        atomicAdd(&hn_s[k], 0.5f * p);
        unsigned short h[16]; float rlo;
        s16x8 hi0, hi1, lo0, lo1;
        #pragma unroll
        for (int i = 0; i < 16; ++i) {
            h[i] = bf16_rn(vv[i]);
            rlo  = vv[i] - bf16_tof(h[i]);
            unsigned short lw = bf16_rn(rlo);
            if (i < 8) { hi0[i]   = (short)h[i]; lo0[i]   = (short)lw; }
            else       { hi1[i-8] = (short)h[i]; lo1[i-8] = (short)lw; }
        }
        const int ks = c0 >> 5;                    // same for both 8-runs
        const int qq = (c0 & 31) >> 3;             // 0 or 2
        Bbuf[buf][ks][0][ qq      * 16 + nn] = hi0;
        Bbuf[buf][ks][0][(qq + 1) * 16 + nn] = hi1;
        Bbuf[buf][ks][1][ qq      * 16 + nn] = lo0;
        Bbuf[buf][ks][1][(qq + 1) * 16 + nn] = lo1;
    };

    stage(0, 0);
    __syncthreads();   // buf 0 + its hn published

    float s1[2][4], s2[2][4]; int k1[2][4];
    #pragma unroll
    for (int i = 0; i < 2; ++i)
        #pragma unroll
        for (int r = 0; r < 4; ++r) { s1[i][r] = -1e30f; s2[i][r] = -1e30f; k1[i][r] = 0; }

    for (int g = 0; g < 64; ++g) {
        const int cur = g & 1;
        if (g + 1 < 64) stage(g + 1, (g + 1) & 1);   // fills other buffer

        f32x4 acc0 = {0.f, 0.f, 0.f, 0.f}, acc1 = {0.f, 0.f, 0.f, 0.f};
        #pragma unroll
        for (int ks = 0; ks < 8; ++ks) {
            s16x8 Bhi = Bbuf[cur][ks][0][l];
            s16x8 Blo = Bbuf[cur][ks][1][l];
            acc0 = __builtin_amdgcn_mfma_f32_16x16x32_bf16(Ahi[0][ks], Bhi, acc0, 0, 0, 0);
            acc1 = __builtin_amdgcn_mfma_f32_16x16x32_bf16(Ahi[1][ks], Bhi, acc1, 0, 0, 0);
            acc0 = __builtin_amdgcn_mfma_f32_16x16x32_bf16(Alo[0][ks], Bhi, acc0, 0, 0, 0);
            acc1 = __builtin_amdgcn_mfma_f32_16x16x32_bf16(Alo[1][ks], Bhi, acc1, 0, 0, 0);
            acc0 = __builtin_amdgcn_mfma_f32_16x16x32_bf16(Ahi[0][ks], Blo, acc0, 0, 0, 0);
            acc1 = __builtin_amdgcn_mfma_f32_16x16x32_bf16(Ahi[1][ks], Blo, acc1, 0, 0, 0);
        }
        const float hnv = hn_s[g * 16 + n];          // code col = lane&15
        const int   kc  = g * 16 + n;
        #pragma unroll
        for (int r = 0; r < 4; ++r) {
            float v0 = acc0[r] - hnv;
            bool c0 = v0 > s1[0][r];
            s2[0][r] = fmaxf(fminf(v0, s1[0][r]), s2[0][r]);   // med3(v,s1,s2)
            s1[0][r] = fmaxf(v0, s1[0][r]);
            k1[0][r] = c0 ? kc : k1[0][r];
            float v1 = acc1[r] - hnv;
            bool c1 = v1 > s1[1][r];
            s2[1][r] = fmaxf(fminf(v1, s1[1][r]), s2[1][r]);
            s1[1][r] = fmaxf(v1, s1[1][r]);
            k1[1][r] = c1 ? kc : k1[1][r];
        }
        __syncthreads();   // publish buf (g+1); buf cur free for stage(g+2)
    }

    // ---- merge top-2 across the 16 code-columns (lanes n=0..15 in each quad) ----
    #pragma unroll
    for (int m = 1; m < 16; m <<= 1) {
        #pragma unroll
        for (int tile = 0; tile < 2; ++tile) {
            #pragma unroll
            for (int r = 0; r < 4; ++r) {
                float o1 = __shfl_xor(s1[tile][r], m, 64);
                float o2 = __shfl_xor(s2[tile][r], m, 64);
                int  ok1 = __shfl_xor(k1[tile][r], m, 64);
                float ns1 = fmaxf(s1[tile][r], o1);
                float ns2 = fmaxf(fminf(s1[tile][r], o1), fmaxf(s2[tile][r], o2));
                k1[tile][r] = (o1 > s1[tile][r]) ? ok1 : k1[tile][r]; // ties flagged anyway
                s1[tile][r] = ns1; s2[tile][r] = ns2;
            }
        }
    }
    if (n == 0) {
        #pragma unroll
        for (int tile = 0; tile < 2; ++tile)
            #pragma unroll
            for (int r = 0; r < 4; ++r) {
                const int p = w * 32 + tile * 16 + q * 4 + r;   // row = quad*4+reg
                s1_s[p] = s1[tile][r]; s2_s[p] = s2[tile][r]; k1_s[p] = k1[tile][r];
            }
    }
    __syncthreads();

    // ---- flag bitmap: waves 0-1 cover pixels 0..127; exclusive words, no atomics
    {
        bool flg = (t < 128) && (s1_s[t] - s2_s[t] < MARGIN);
        unsigned long long m = __ballot(flg);
        if (w < 2 && l == 0 && m) {
            const int base = (pix0 + w * 64) >> 5;
            unsigned lo = (unsigned)m, hi = (unsigned)(m >> 32);
            if (lo) g_bitmap[base]     = lo;
            if (hi) g_bitmap[base + 1] = hi;
        }
    }

    // ---- gather + NCHW write (flagged pixels overwritten by rescan kernel) ----
    {
        const int p = t & 127;
        const int ch0 = t >> 7;                    // 0 or 1
        const float* crow = cb + (size_t)k1_s[p] * DIM + ch0;
        float* orow = out + (size_t)b * DIM * HWSZ + (size_t)ch0 * HWSZ + hw0 + p;
        #pragma unroll 8
        for (int cc = 0; cc < 128; ++cc)
            orow[(size_t)cc * 2 * HWSZ] = crow[cc * 2];
    }
}

// ---- kernel 2: numpy-bitwise rescan of flagged pixels (round-3-validated math) ----
__global__ __launch_bounds__(256, 2)
void kvq_rescan(const float* __restrict__ z, const float* __restrict__ cb,
                float* __restrict__ out) {
    __shared__ float t2_s[KCODES];
    __shared__ __align__(16) float zpix[DIM];
    __shared__ float t1_sh;
    __shared__ float rbs[256];
    __shared__ int   rbk[256];
    __shared__ int   flist[128];
    __shared__ int   fcnt;

    const int t = threadIdx.x;
    const int pix0 = blockIdx.x * 128;
    const int b   = pix0 >> 12;
    const int hw0 = pix0 & 4095;

    if (t == 0) {
        int c = 0;
        #pragma unroll
        for (int wd = 0; wd < 4; ++wd) {
            unsigned m = g_bitmap[(pix0 >> 5) + wd];
            while (m) {
                int bpos = __ffs(m) - 1;
                m &= m - 1;
                flist[c++] = wd * 32 + bpos;     // ascending pixel order
            }
        }
        fcnt = c;
    }
    __syncthreads();
    const int cnt = fcnt;
    if (cnt == 0) return;

    #pragma unroll
    for (int j = 0; j < 4; ++j) t2_s[t + 256 * j] = g_t2[t + 256 * j];
    __syncthreads();

    for (int f = 0; f < cnt; ++f) {
        const int p = flist[f];
        zpix[t] = z[((size_t)(b * DIM + t)) * HWSZ + hw0 + p];
        __syncthreads();
        if (t == 0) t1_sh = np_sumsq_row((const float4*)zpix);
        float sj[4];
        #pragma unroll
        for (int j = 0; j < 4; ++j) {
            const int k = t + 256 * j;
            sj[j] = np_dot_sse((const float4*)zpix, (const float4*)(cb + (size_t)k * DIM));
        }
        __syncthreads();
        const float t1v = t1_sh;
        float bd = 1e30f; int bk = 1 << 30;
        #pragma unroll
        for (int j = 0; j < 4; ++j) {          // k ascending within thread
            float d = np_d(t1v, t2_s[t + 256 * j], sj[j]);
            if (d < bd) { bd = d; bk = t + 256 * j; }
        }
        rbs[t] = bd; rbk[t] = bk;
        __syncthreads();
        for (int st = 128; st; st >>= 1) {
            if (t < st) {
                if (rbs[t + st] < rbs[t] ||
                    (rbs[t + st] == rbs[t] && rbk[t + st] < rbk[t])) {
                    rbs[t] = rbs[t + st]; rbk[t] = rbk[t + st];
                }
            }
            __syncthreads();
        }
        const int K = rbk[0];
        out[((size_t)(b * DIM + t)) * HWSZ + hw0 + p] = cb[(size_t)K * DIM + t];
        __syncthreads();
    }
}

extern "C" void kernel_launch(void* const* d_in, const int* in_sizes, int n_in,
                              void* d_out, int out_size, void* d_ws, size_t ws_size,
                              hipStream_t stream) {
    const float* z  = (const float*)d_in[0];
    const float* cb = (const float*)d_in[1];
    float* out = (float*)d_out;
    (void)d_ws; (void)ws_size;
    kvq_t2<<<KCODES / 256, 256, 0, stream>>>(cb);
    kvq_coarse<<<NPIX / 128, 256, 0, stream>>>(z, cb, out);
    kvq_rescan<<<NPIX / 128, 256, 0, stream>>>(z, cb, out);
}

// Round 4
// 663.774 us; speedup vs baseline: 8.5614x; 5.4276x over previous
//
#include <hip/hip_runtime.h>

// VQ: z [32,256,64,64] f32, codebook [1024,256] f32 -> out [32,256,64,64] f32
// 3 kernels:
//  kvq_prep  : np-exact ||e||^2 table, hn = 0.5*||e||^2, frag-ordered split-bf16
//              codebook (bitwise same bf16_rn math as the old per-block stage),
//              worklist counter reset.
//  kvq_coarse: bf16 double-split MFMA coarse top-2 (identical MFMA inputs),
//              gather write, flagged pixels appended to global worklist.
//  kvq_rescan: numpy-bitwise full rescan, 8-pixel-batched per block so each
//              codebook row load is amortized over 8 pixels (was 1 scan/pixel
//              -> 5.5 GB HBM + serial per-block processing = 2950 us).
// Per-(pixel,code) rescan math is verbatim round-3-validated (contract off,
// same accumulation order; partial unroll pragmas bound codegen size without
// reordering any accumulator chain); argmin reduction is exact lexicographic
// (d,k) min, so reduction shape is free.

typedef float  f32x4 __attribute__((ext_vector_type(4)));
typedef short  s16x8 __attribute__((ext_vector_type(8)));

#define HWSZ   4096
#define DIM    256
#define KCODES 1024
#define MARGIN 1e-4f
#define NPIX   131072
#define NB     8

__device__ float g_t2[KCODES];
__device__ float g_hn[KCODES];
__device__ int   g_fcnt;
__device__ int   g_flist[NPIX];
__device__ s16x8 g_cbsplit[64][8][2][64];   // 1 MB: [group][ks][hi/lo][lane]

__device__ __forceinline__ unsigned short bf16_rn(float f) {
    unsigned u = __float_as_uint(f);
    unsigned r = u + 0x7fffu + ((u >> 16) & 1u);
    return (unsigned short)(r >> 16);
}
__device__ __forceinline__ float bf16_tof(unsigned short h) {
    return __uint_as_float(((unsigned)h) << 16);
}

// ---- numpy-bitwise helpers (validated round 3): fp contraction OFF ----
__device__ __forceinline__ float np_sumsq_row(const float4* v4) {
    #pragma clang fp contract(off)
    float res0 = 0.f, res1 = 0.f;
    for (int h = 0; h < 2; ++h) {
        const float4* p = v4 + h * 32;          // 128 floats
        float4 a = p[0], b = p[1];
        float r0 = a.x*a.x, r1 = a.y*a.y, r2 = a.z*a.z, r3 = a.w*a.w;
        float r4 = b.x*b.x, r5 = b.y*b.y, r6 = b.z*b.z, r7 = b.w*b.w;
        for (int i = 1; i < 16; ++i) {
            a = p[2*i]; b = p[2*i+1];
            r0 += a.x*a.x; r1 += a.y*a.y; r2 += a.z*a.z; r3 += a.w*a.w;
            r4 += b.x*b.x; r5 += b.y*b.y; r6 += b.z*b.z; r7 += b.w*b.w;
        }
        float s = ((r0+r1)+(r2+r3))+((r4+r5)+(r6+r7));
        if (h == 0) res0 = s; else res1 = s;
    }
    return res0 + res1;
}
__device__ __forceinline__ float np_d(float t1, float t2, float s) {
    #pragma clang fp contract(off)
    float T = t1 + t2;
    float U = 2.0f * s;
    return T - U;
}

// ---- kernel 0: tables + split codebook + counter reset ----
__global__ void kvq_prep(const float* __restrict__ cb) {
    const int k = blockIdx.x * 256 + threadIdx.x;   // 0..1023
    if (k == 0) g_fcnt = 0;
    const float t2 = np_sumsq_row((const float4*)(cb + (size_t)k * DIM));
    g_t2[k] = t2;
    g_hn[k] = 0.5f * t2;
    const int g = k >> 4, nn = k & 15;
    #pragma unroll 2
    for (int c0 = 0; c0 < DIM; c0 += 16) {
        float vv[16];
        #pragma unroll
        for (int i = 0; i < 16; ++i) vv[i] = cb[(size_t)k * DIM + c0 + i];
        s16x8 hi0, hi1, lo0, lo1;
        #pragma unroll
        for (int i = 0; i < 16; ++i) {
            unsigned short h = bf16_rn(vv[i]);
            float r = vv[i] - bf16_tof(h);
            unsigned short lw = bf16_rn(r);
            if (i < 8) { hi0[i]   = (short)h; lo0[i]   = (short)lw; }
            else       { hi1[i-8] = (short)h; lo1[i-8] = (short)lw; }
        }
        const int ks = c0 >> 5;                    // matches old stage()
        const int qq = (c0 & 31) >> 3;             // 0 or 2
        g_cbsplit[g][ks][0][ qq      * 16 + nn] = hi0;
        g_cbsplit[g][ks][0][(qq + 1) * 16 + nn] = hi1;
        g_cbsplit[g][ks][1][ qq      * 16 + nn] = lo0;
        g_cbsplit[g][ks][1][(qq + 1) * 16 + nn] = lo1;
    }
}

// ---- kernel 1: coarse top-2 + gather write + worklist append ----
__global__ __launch_bounds__(256, 2)
void kvq_coarse(const float* __restrict__ z, const float* __restrict__ cb,
                float* __restrict__ out) {
    __shared__ s16x8 Bbuf[2][8][2][64];   // [buf][kstep][hi/lo][lane] 16B frags, 32 KB
    __shared__ float hn_s[KCODES];
    __shared__ float s1_s[128], s2_s[128];
    __shared__ int   k1_s[128];

    const int t = threadIdx.x;
    const int l = t & 63, w = t >> 6;     // lane, wave
    const int n = l & 15, q = l >> 4;     // frag col / quad
    const int pix0 = blockIdx.x * 128;    // 128 pixels per block
    const int b   = pix0 >> 12;
    const int hw0 = pix0 & 4095;

    for (int i = t; i < KCODES; i += 256) hn_s[i] = g_hn[i];

    // ---- A fragments: wave w owns pixels [w*32, w*32+32). tile 0/1 = 16 pixels.
    s16x8 Ahi[2][8], Alo[2][8];
    #pragma unroll
    for (int tile = 0; tile < 2; ++tile) {
        const float* zp = z + (size_t)b * DIM * HWSZ + hw0 + w * 32 + tile * 16 + n;
        #pragma unroll
        for (int ks = 0; ks < 8; ++ks) {
            #pragma unroll
            for (int j = 0; j < 8; ++j) {
                float v = zp[(size_t)(ks * 32 + q * 8 + j) * HWSZ];
                unsigned short h = bf16_rn(v);
                float r = v - bf16_tof(h);
                Ahi[tile][ks][j] = (short)h;
                Alo[tile][ks][j] = (short)bf16_rn(r);
            }
        }
    }

    // ---- B staging: pure 16 KB copy from pre-split codebook ----
    auto stage = [&](int g, int buf) {
        const s16x8* src = &g_cbsplit[g][0][0][0];
        s16x8* dst = &Bbuf[buf][0][0][0];
        #pragma unroll
        for (int i = 0; i < 4; ++i) dst[t + 256 * i] = src[t + 256 * i];
    };

    stage(0, 0);
    __syncthreads();   // buf 0 + hn_s published

    float s1[2][4], s2[2][4]; int k1[2][4];
    #pragma unroll
    for (int i = 0; i < 2; ++i)
        #pragma unroll
        for (int r = 0; r < 4; ++r) { s1[i][r] = -1e30f; s2[i][r] = -1e30f; k1[i][r] = 0; }

    for (int g = 0; g < 64; ++g) {
        const int cur = g & 1;
        if (g + 1 < 64) stage(g + 1, (g + 1) & 1);   // fills other buffer

        f32x4 acc0 = {0.f, 0.f, 0.f, 0.f}, acc1 = {0.f, 0.f, 0.f, 0.f};
        #pragma unroll
        for (int ks = 0; ks < 8; ++ks) {
            s16x8 Bhi = Bbuf[cur][ks][0][l];
            s16x8 Blo = Bbuf[cur][ks][1][l];
            acc0 = __builtin_amdgcn_mfma_f32_16x16x32_bf16(Ahi[0][ks], Bhi, acc0, 0, 0, 0);
            acc1 = __builtin_amdgcn_mfma_f32_16x16x32_bf16(Ahi[1][ks], Bhi, acc1, 0, 0, 0);
            acc0 = __builtin_amdgcn_mfma_f32_16x16x32_bf16(Alo[0][ks], Bhi, acc0, 0, 0, 0);
            acc1 = __builtin_amdgcn_mfma_f32_16x16x32_bf16(Alo[1][ks], Bhi, acc1, 0, 0, 0);
            acc0 = __builtin_amdgcn_mfma_f32_16x16x32_bf16(Ahi[0][ks], Blo, acc0, 0, 0, 0);
            acc1 = __builtin_amdgcn_mfma_f32_16x16x32_bf16(Ahi[1][ks], Blo, acc1, 0, 0, 0);
        }
        const float hnv = hn_s[g * 16 + n];          // code col = lane&15
        const int   kc  = g * 16 + n;
        #pragma unroll
        for (int r = 0; r < 4; ++r) {
            float v0 = acc0[r] - hnv;
            bool c0 = v0 > s1[0][r];
            s2[0][r] = fmaxf(fminf(v0, s1[0][r]), s2[0][r]);   // med3(v,s1,s2)
            s1[0][r] = fmaxf(v0, s1[0][r]);
            k1[0][r] = c0 ? kc : k1[0][r];
            float v1 = acc1[r] - hnv;
            bool c1 = v1 > s1[1][r];
            s2[1][r] = fmaxf(fminf(v1, s1[1][r]), s2[1][r]);
            s1[1][r] = fmaxf(v1, s1[1][r]);
            k1[1][r] = c1 ? kc : k1[1][r];
        }
        __syncthreads();   // publish buf (g+1); buf cur free for stage(g+2)
    }

    // ---- merge top-2 across the 16 code-columns ----
    #pragma unroll
    for (int m = 1; m < 16; m <<= 1) {
        #pragma unroll
        for (int tile = 0; tile < 2; ++tile) {
            #pragma unroll
            for (int r = 0; r < 4; ++r) {
                float o1 = __shfl_xor(s1[tile][r], m, 64);
                float o2 = __shfl_xor(s2[tile][r], m, 64);
                int  ok1 = __shfl_xor(k1[tile][r], m, 64);
                float ns1 = fmaxf(s1[tile][r], o1);
                float ns2 = fmaxf(fminf(s1[tile][r], o1), fmaxf(s2[tile][r], o2));
                k1[tile][r] = (o1 > s1[tile][r]) ? ok1 : k1[tile][r]; // ties flagged anyway
                s1[tile][r] = ns1; s2[tile][r] = ns2;
            }
        }
    }
    if (n == 0) {
        #pragma unroll
        for (int tile = 0; tile < 2; ++tile)
            #pragma unroll
            for (int r = 0; r < 4; ++r) {
                const int p = w * 32 + tile * 16 + q * 4 + r;   // row = quad*4+reg
                s1_s[p] = s1[tile][r]; s2_s[p] = s2[tile][r]; k1_s[p] = k1[tile][r];
            }
    }
    __syncthreads();

    // ---- flagged pixels -> global worklist ----
    if (t < 128 && (s1_s[t] - s2_s[t] < MARGIN)) {
        int pos = atomicAdd(&g_fcnt, 1);
        g_flist[pos] = pix0 + t;
    }

    // ---- gather + NCHW write (flagged pixels overwritten by rescan kernel) ----
    {
        const int p = t & 127;
        const int ch0 = t >> 7;                    // 0 or 1
        const float* crow = cb + (size_t)k1_s[p] * DIM + ch0;
        float* orow = out + (size_t)b * DIM * HWSZ + (size_t)ch0 * HWSZ + hw0 + p;
        #pragma unroll 8
        for (int cc = 0; cc < 128; ++cc)
            orow[(size_t)cc * 2 * HWSZ] = crow[cc * 2];
    }
}

// ---- kernel 2: numpy-bitwise rescan, 8-pixel batches per block ----
__global__ __launch_bounds__(256, 2)
void kvq_rescan(const float* __restrict__ z, const float* __restrict__ cb,
                float* __restrict__ out) {
    #pragma clang fp contract(off)
    __shared__ __align__(16) float zl[NB][DIM];    // 8 KB
    __shared__ float t1_s[NB];
    __shared__ int   pl[NB];
    __shared__ float wbs[NB][4];
    __shared__ int   wbk[NB][4];
    __shared__ int   kb_s[NB];

    const int t = threadIdx.x;
    const int l = t & 63, w = t >> 6;
    const int cnt = g_fcnt;

    for (int base = blockIdx.x * NB; base < cnt; base += gridDim.x * NB) {
        // pad short batches with the last valid pixel (recomputed -> same write)
        if (t < NB) pl[t] = g_flist[min(base + t, cnt - 1)];
        __syncthreads();
        #pragma unroll
        for (int p = 0; p < NB; ++p) {
            const int pix = pl[p];
            zl[p][t] = z[((size_t)((pix >> 12) * DIM + t)) * HWSZ + (pix & 4095)];
        }
        __syncthreads();
        if (t < NB) t1_s[t] = np_sumsq_row((const float4*)zl[t]);

        // thread t owns codes t+256j; each row streamed once for all 8 pixels.
        // Per-pixel accumulation order identical to np_dot_sse (A0..A3, i asc;
        // partial unroll does not reorder any single accumulator's chain).
        float sj[NB][4];
        #pragma unroll
        for (int j = 0; j < 4; ++j) {
            const float4* e4 = (const float4*)(cb + (size_t)(t + 256 * j) * DIM);
            float A0[NB], A1[NB], A2[NB], A3[NB];
            #pragma unroll
            for (int p = 0; p < NB; ++p) { A0[p]=0.f; A1[p]=0.f; A2[p]=0.f; A3[p]=0.f; }
            #pragma unroll 4
            for (int i = 0; i < 64; ++i) {
                float4 ev = e4[i];
                #pragma unroll
                for (int p = 0; p < NB; ++p) {
                    float4 zv = ((const float4*)zl[p])[i];
                    A0[p] += zv.x*ev.x; A1[p] += zv.y*ev.y;
                    A2[p] += zv.z*ev.z; A3[p] += zv.w*ev.w;
                }
            }
            #pragma unroll
            for (int p = 0; p < NB; ++p) sj[p][j] = (A0[p]+A1[p])+(A2[p]+A3[p]);
        }
        __syncthreads();   // t1_s visible

        float bd[NB]; int bk[NB];
        #pragma unroll
        for (int p = 0; p < NB; ++p) {
            const float t1v = t1_s[p];
            bd[p] = 1e30f; bk[p] = 1 << 30;
            #pragma unroll
            for (int j = 0; j < 4; ++j) {          // k ascending, strict < (np argmin)
                float d = np_d(t1v, g_t2[t + 256 * j], sj[p][j]);
                if (d < bd[p]) { bd[p] = d; bk[p] = t + 256 * j; }
            }
        }
        // exact lexicographic (d,k) min: wave butterfly then cross-wave
        #pragma unroll
        for (int m = 1; m < 64; m <<= 1) {
            #pragma unroll
            for (int p = 0; p < NB; ++p) {
                float od = __shfl_xor(bd[p], m, 64);
                int   ok = __shfl_xor(bk[p], m, 64);
                if (od < bd[p] || (od == bd[p] && ok < bk[p])) { bd[p] = od; bk[p] = ok; }
            }
        }
        if (l == 0) {
            #pragma unroll
            for (int p = 0; p < NB; ++p) { wbs[p][w] = bd[p]; wbk[p][w] = bk[p]; }
        }
        __syncthreads();
        if (t < NB) {
            float B = wbs[t][0]; int K = wbk[t][0];
            #pragma unroll
            for (int w2 = 1; w2 < 4; ++w2) {
                if (wbs[t][w2] < B || (wbs[t][w2] == B && wbk[t][w2] < K)) {
                    B = wbs[t][w2]; K = wbk[t][w2];
                }
            }
            kb_s[t] = K;
        }
        __syncthreads();
        #pragma unroll
        for (int p = 0; p < NB; ++p) {
            const int pix = pl[p];
            out[((size_t)((pix >> 12) * DIM + t)) * HWSZ + (pix & 4095)] =
                cb[(size_t)kb_s[p] * DIM + t];
        }
        __syncthreads();   // protect pl/zl for next batch
    }
}

extern "C" void kernel_launch(void* const* d_in, const int* in_sizes, int n_in,
                              void* d_out, int out_size, void* d_ws, size_t ws_size,
                              hipStream_t stream) {
    const float* z  = (const float*)d_in[0];
    const float* cb = (const float*)d_in[1];
    float* out = (float*)d_out;
    (void)d_ws; (void)ws_size;
    kvq_prep<<<KCODES / 256, 256, 0, stream>>>(cb);
    kvq_coarse<<<NPIX / 128, 256, 0, stream>>>(z, cb, out);
    kvq_rescan<<<1024, 256, 0, stream>>>(z, cb, out);
}